// Round 13
// baseline (258.269 us; speedup 1.0000x reference)
//
#include <hip/hip_runtime.h>
#include <hip/hip_bf16.h>

#define B_ 8
#define G_ 256
#define N_ 1024
#define P_ 4
#define F_ 256
#define KHOP 4
#define KG_ (KHOP * G_)   // 1024

// ---------------------------------------------------------------------------
// GLOBAL TILED LAYOUT (shared by expT, fwbf, xT, sA/sB):
//   matrix [R rows][C k-cols] -> tiles [R/128][C/64], each tile 8192 ushorts
//   (16 KB) contiguous.  Within a tile, element (r,k), r<128, k<64:
//     cell = (r>>4)*2 + (k>>5)            [0..15]
//     lane = ((k>>3)&3)*16 + (r&15)       [0..63]
//     e    = k&7
//     flat = cell*512 + lane*8 + e
//   One cell = one 16x32 MFMA fragment in exact lane order.
// ---------------------------------------------------------------------------

typedef unsigned short ushort_t;
typedef __bf16 bf16x8 __attribute__((ext_vector_type(8)));
typedef unsigned short u16x8 __attribute__((ext_vector_type(8)));
typedef float f32x4 __attribute__((ext_vector_type(4)));

__device__ __forceinline__ unsigned short f2bf(float f) {
  union { float fl; unsigned int i; } v; v.fl = f;
  return (unsigned short)((v.i + 0x7fffu + ((v.i >> 16) & 1u)) >> 16);
}

__device__ __forceinline__ void gload_lds16(const ushort_t* g, ushort_t* l) {
  __builtin_amdgcn_global_load_lds(
      (const __attribute__((address_space(1))) void*)g,
      (__attribute__((address_space(3))) void*)l, 16, 0, 0);
}

// ---------------------------------------------------------------------------
// K-PREP  (unchanged)
__global__ __launch_bounds__(256) void k_prep(
    const float* __restrict__ x, const float* __restrict__ mixer,
    const float* __restrict__ weight, const float* __restrict__ wb,
    const float* __restrict__ fw, float* __restrict__ e1, float* __restrict__ e2,
    ushort_t* __restrict__ fwbf, ushort_t* __restrict__ xT,
    float* __restrict__ sumb) {
  int blk = blockIdx.x;
  int t = threadIdx.x;
  if (blk < 128) {
    __shared__ float s1[G_], s2[G_];
    __shared__ float cred[2][4];
    int bp = blk >> 2;
    int nc = blk & 3;
    int b = bp >> 2, p = bp & (P_ - 1);
    int n = nc * 256 + t;
    float acc1 = 0.f, acc2 = 0.f;
    const float* wp = weight + (size_t)p * F_ * G_ + t;
    const float* mp = mixer + p * 2 * F_;
    for (int f = 0; f < F_; ++f) {
      float wv = wp[(size_t)f * G_];
      acc1 = fmaf(mp[f], wv, acc1);
      acc2 = fmaf(mp[F_ + f], wv, acc2);
    }
    s1[t] = acc1;
    s2[t] = acc2;
    float c1p = mp[t] * wb[p * F_ + t];
    float c2p = mp[F_ + t] * wb[p * F_ + t];
#pragma unroll
    for (int mask = 1; mask < 64; mask <<= 1) {
      c1p += __shfl_xor(c1p, mask, 64);
      c2p += __shfl_xor(c2p, mask, 64);
    }
    if ((t & 63) == 0) {
      cred[0][t >> 6] = c1p;
      cred[1][t >> 6] = c2p;
    }
    __syncthreads();
    float c1 = cred[0][0] + cred[0][1] + cred[0][2] + cred[0][3];
    float c2 = cred[1][0] + cred[1][1] + cred[1][2] + cred[1][3];
    const float* xb = x + (size_t)b * G_ * N_ + n;
    float a1 = 0.f, a2 = 0.f;
#pragma unroll 8
    for (int g = 0; g < G_; ++g) {
      float xv = xb[(size_t)g * N_];
      a1 = fmaf(s1[g], xv, a1);
      a2 = fmaf(s2[g], xv, a2);
    }
    e1[(size_t)bp * N_ + n] = c1 + a1;
    e2[(size_t)bp * N_ + n] = c2 + a2;
  } else if (blk < 256) {
    int tile = blk - 128;            // 0..127
    int p = tile >> 5;
    int mb = (tile >> 4) & 1;
    int kb = tile & 15;
    int w = t >> 6, lane = t & 63;
    size_t tbase = ((size_t)(p * 2 + mb) * 16 + kb) * 8192;
#pragma unroll
    for (int q = 0; q < 4; ++q) {
      int cell = q * 4 + w;
      int f = mb * 128 + (cell >> 1) * 16 + (lane & 15);
      int kg = kb * 64 + (cell & 1) * 32 + (lane >> 4) * 8;
      const float* s = fw + ((size_t)p * F_ + f) * KG_ + kg;
      float4 v0 = *(const float4*)&s[0];
      float4 v1 = *(const float4*)&s[4];
      u16x8 o;
      o[0] = f2bf(v0.x); o[1] = f2bf(v0.y); o[2] = f2bf(v0.z); o[3] = f2bf(v0.w);
      o[4] = f2bf(v1.x); o[5] = f2bf(v1.y); o[6] = f2bf(v1.z); o[7] = f2bf(v1.w);
      *(u16x8*)&fwbf[tbase + (size_t)cell * 512 + lane * 8] = o;
    }
  } else if (blk < 768) {
    __shared__ ushort_t tile[64][66];
    int idx = blk - 256;
    int n0 = (idx & 15) * 64;
    int g0 = ((idx >> 4) & 3) * 64;
    int b = idx >> 6;
    int rr = t >> 4, cc = (t & 15) * 4;
#pragma unroll
    for (int ps = 0; ps < 4; ++ps) {
      float4 v = *(const float4*)&x[((size_t)b * G_ + g0 + ps * 16 + rr) * N_ + n0 + cc];
      tile[ps * 16 + rr][cc] = f2bf(v.x);
      tile[ps * 16 + rr][cc + 1] = f2bf(v.y);
      tile[ps * 16 + rr][cc + 2] = f2bf(v.z);
      tile[ps * 16 + rr][cc + 3] = f2bf(v.w);
    }
    __syncthreads();
    int w = t >> 6, lane = t & 63;
    int nb = n0 >> 7;                 // 0..7
    int kb = g0 >> 6;                 // 0..3
    int rhalf = (n0 & 64) >> 4;       // 0 or 4
    size_t tbase = ((size_t)(b * 8 + nb) * 4 + kb) * 8192;
#pragma unroll
    for (int q = 0; q < 2; ++q) {
      int cl = q * 4 + w;                         // 0..7 local cell
      int cell = (rhalf + (cl >> 1)) * 2 + (cl & 1);
      int nl = (cl >> 1) * 16 + (lane & 15);      // 0..63 local n
      int gl = (cl & 1) * 32 + (lane >> 4) * 8;   // 0..56
      u16x8 v;
#pragma unroll
      for (int j = 0; j < 8; ++j) v[j] = tile[gl + j][nl];
      *(u16x8*)&xT[tbase + (size_t)cell * 512 + lane * 8] = v;
    }
  } else {
    int i = (blk - 768) * 256 + t;
    sumb[i] = 0.f;
  }
}

// ---------------------------------------------------------------------------
// K5 v2: one block serves ALL 4 p (S/mask read once).  (unchanged)
__global__ __launch_bounds__(256) void k_att(const float* __restrict__ e1,
                                             const float* __restrict__ e2,
                                             const float* __restrict__ S,
                                             ushort_t* __restrict__ expT,
                                             float* __restrict__ sumb) {
  __shared__ ushort_t tile[256][72];   // [j-local][i-local]
  __shared__ float se1[P_][256];
  __shared__ float se2[P_][64];
  int b = blockIdx.z;          // 0..7
  int i0 = blockIdx.y * 64;    // k-dim chunk
  int j0 = blockIdx.x * 256;   // n-dim chunk
  int t = threadIdx.x;
  int rr = t >> 4;
  int cc4 = t & 15;
  int cc = cc4 * 4;

#pragma unroll
  for (int p = 0; p < P_; ++p) {
    int bp = b * 4 + p;
    se1[p][t] = e1[(size_t)bp * N_ + j0 + t];
    if (t < 64) se2[p][t] = e2[(size_t)bp * N_ + i0 + t];
  }
  __syncthreads();

  const float* Sb = S + (size_t)b * N_ * N_;
  unsigned long long mbits = 0ull;
#pragma unroll
  for (int js = 0; js < 4; ++js) {
#pragma unroll
    for (int ps = 0; ps < 4; ++ps) {
      int il = ps * 16 + rr;
      float4 s4 = *(const float4*)&Sb[(size_t)(i0 + il) * N_ + j0 + js * 64 + cc];
      float sv[4] = {s4.x, s4.y, s4.z, s4.w};
#pragma unroll
      for (int s = 0; s < 4; ++s)
        if (fabsf(sv[s]) > 1e-9f)
          mbits |= 1ull << (js * 16 + ps * 4 + s);
    }
  }

  int w = t >> 6, lane = t & 63;
  int kb = i0 >> 6;
  for (int p = 0; p < P_; ++p) {
    int bp = b * 4 + p;
    float re2[4];
#pragma unroll
    for (int ps = 0; ps < 4; ++ps) re2[ps] = se2[p][ps * 16 + rr];
    float psum[4] = {0.f, 0.f, 0.f, 0.f};
#pragma unroll
    for (int js = 0; js < 4; ++js) {
      float4 e1q = *(float4*)&se1[p][js * 64 + cc];
      float e1v[4] = {e1q.x, e1q.y, e1q.z, e1q.w};
#pragma unroll
      for (int ps = 0; ps < 4; ++ps) {
        int il = ps * 16 + rr;
#pragma unroll
        for (int s = 0; s < 4; ++s) {
          float v = e1v[s] + re2[ps];
          float l = v >= 0.f ? v : 0.2f * v;
          bool m = (mbits >> (js * 16 + ps * 4 + s)) & 1ull;
          float e = m ? __expf(l) : 0.f;
          psum[ps] += e;
          tile[js * 64 + cc + s][il] = f2bf(e);
        }
      }
    }
#pragma unroll
    for (int mask = 1; mask < 16; mask <<= 1) {
#pragma unroll
      for (int ps = 0; ps < 4; ++ps) psum[ps] += __shfl_xor(psum[ps], mask, 64);
    }
    if (cc4 == 0) {
#pragma unroll
      for (int ps = 0; ps < 4; ++ps)
        atomicAdd(&sumb[(size_t)bp * N_ + i0 + ps * 16 + rr], psum[ps]);
    }
    __syncthreads();
#pragma unroll
    for (int hb = 0; hb < 2; ++hb) {
      size_t tbase = ((size_t)(bp * 8 + (j0 >> 7) + hb) * 16 + kb) * 8192;
#pragma unroll
      for (int q = 0; q < 4; ++q) {
        int cell = q * 4 + w;
        int r = (cell >> 1) * 16 + (lane & 15);
        int il = (cell & 1) * 32 + (lane >> 4) * 8;
        u16x8 v = *(const u16x8*)&tile[hb * 128 + r][il];
        *(u16x8*)&expT[tbase + (size_t)cell * 512 + lane * 8] = v;
      }
    }
    __syncthreads();   // tile reads done before next p overwrites
  }
}

// ---------------------------------------------------------------------------
// K6 v12: v7 structure at DOUBLE TLP.  128x128 tile, but 512 threads =
// 8 waves (2m x 4n, wave tile 64x32).  Grid stays 512 -> 2 blocks/CU x
// 8 waves = 4 waves/SIMD (was 2): twice the latency-hiding pool, which is
// what every profile said was missing (grid-capped occupancy ~18%).
// Loop body proven pieces unchanged: tiled-global layout, B through
// double-buffered LDS via global_load_lds, counted vmcnt, A fragments
// direct global->VGPR.  Per wave per iter: 8 A-loads + 2 stageB DMA are
// younger than B_cur -> vmcnt(10).
__global__ __launch_bounds__(512, 4) void gemm_step(
    const ushort_t* __restrict__ Aprev, const ushort_t* __restrict__ Bt,
    const ushort_t* __restrict__ fwbf, const ushort_t* __restrict__ xT,
    const float* __restrict__ bias, const float* __restrict__ sumb,
    ushort_t* __restrict__ outb, float* __restrict__ outf,
    int kslice, int has_prev, int last) {
  __shared__ ushort_t Bs[2][8192];   // 16 KB per buf; also epilogue scratch
  // ---- XCD-aware decode: id&7 = xcd, 4 bps per XCD, 16 blocks per bp ----
  int id = blockIdx.x;
  int xcd = id & 7;
  int slot = id >> 3;            // 0..63
  int bp = xcd * 4 + (slot >> 4);
  int inner = slot & 15;
  int mb = inner >> 3;           // 0..1
  int m0 = mb * 128;
  int nb = inner & 7;            // 0..7
  int n0 = nb * 128;
  int p = bp & (P_ - 1), b = bp >> 2;
  int t = threadIdx.x;
  int lane = t & 63;
  int w = t >> 6;                // 0..7
  int wm = w >> 2, wn = w & 3;   // 2m x 4n wave grid, wave tile 64x32
  int lr = lane & 15, quad = lane >> 4;
  int laneoff = lane * 8;

  const ushort_t* A1 = has_prev ? (Aprev + (size_t)(bp * 2 + mb) * 16 * 8192) : fwbf;
  const ushort_t* A2 = fwbf + ((size_t)(p * 2 + mb) * 16 + kslice * 4) * 8192;
  const ushort_t* B1 = Bt + (size_t)(bp * 8 + nb) * 16 * 8192;
  const ushort_t* B2 = xT + (size_t)(b * 8 + nb) * 4 * 8192;

  const int ntA = has_prev ? (N_ / 64) : 0;   // 16 or 0
  const int NT = ntA + G_ / 64;               // 20 or 4

  f32x4 acc[4][2] = {};

  auto stageB = [&](int it, int buf) {
    const ushort_t* Bb = (it < ntA) ? B1 + (size_t)it * 8192
                                    : B2 + (size_t)(it - ntA) * 8192;
#pragma unroll
    for (int l = 0; l < 2; ++l) {
      int coff = (w * 2 + l) * 512;
      gload_lds16(Bb + coff + laneoff, &Bs[buf][coff]);
    }
  };

  // prologue: stage B tile 0 into buf 0 (2 loads/wave in flight)
  stageB(0, 0);
  int cur = 0;
  for (int it = 0; it < NT; ++it) {
    const ushort_t* At = (it < ntA) ? A1 + (size_t)it * 8192
                                    : A2 + (size_t)(it - ntA) * 8192;
    // A fragments: direct global->VGPR (wave-contiguous 1 KB each)
    u16x8 afr[2][4];
#pragma unroll
    for (int c = 0; c < 2; ++c)
#pragma unroll
      for (int mi = 0; mi < 4; ++mi)
        afr[c][mi] = *(const u16x8*)&At[(((wm * 4 + mi) * 2) + c) * 512 + laneoff];
    __builtin_amdgcn_sched_barrier(0);   // pin: afr issued before B_next DMA
    if (it + 1 < NT) {
      stageB(it + 1, cur ^ 1);                          // 2 more in flight
      asm volatile("s_waitcnt vmcnt(10)" ::: "memory"); // B_cur landed
    } else {
      asm volatile("s_waitcnt vmcnt(0)" ::: "memory");
    }
    __builtin_amdgcn_s_barrier();        // all waves' B_cur DMA visible
#pragma unroll
    for (int c = 0; c < 2; ++c) {
      bf16x8 bfr[2];
#pragma unroll
      for (int ni = 0; ni < 2; ++ni)
        bfr[ni] = __builtin_bit_cast(bf16x8,
            *(const u16x8*)&Bs[cur][(((wn * 2 + ni) * 2) + c) * 512 + lane * 8]);
#pragma unroll
      for (int mi = 0; mi < 4; ++mi) {
        bf16x8 af = __builtin_bit_cast(bf16x8, afr[c][mi]);
#pragma unroll
        for (int ni = 0; ni < 2; ++ni)
          acc[mi][ni] = __builtin_amdgcn_mfma_f32_16x16x32_bf16(af, bfr[ni], acc[mi][ni], 0, 0, 0);
      }
    }
    __builtin_amdgcn_s_barrier();        // reads done before buf overwritten
    cur ^= 1;
  }

  if (last) {
    float* Ob = outf + (size_t)bp * (F_ * N_);
#pragma unroll
    for (int mi = 0; mi < 4; ++mi) {
      int fbase = m0 + wm * 64 + mi * 16 + quad * 4;
#pragma unroll
      for (int ni = 0; ni < 2; ++ni) {
        int n = n0 + wn * 32 + ni * 16 + lr;
#pragma unroll
        for (int r = 0; r < 4; ++r) {
          float v = acc[mi][ni][r] + bias[fbase + r];
          Ob[(size_t)(fbase + r) * N_ + n] = v >= 0.f ? v : 0.01f * v;
        }
      }
    }
  } else {
    // epilogue via LDS scratch -> tiled global layout (next step's A)
    ushort_t* scratch = &Bs[0][0];   // 16384 ushorts = 32 KB
    float iv[2];
#pragma unroll
    for (int ni = 0; ni < 2; ++ni)
      iv[ni] = 1.0f / sumb[(size_t)bp * N_ + n0 + wn * 32 + ni * 16 + lr];
#pragma unroll
    for (int mi = 0; mi < 4; ++mi) {
#pragma unroll
      for (int ni = 0; ni < 2; ++ni) {
        int nL = wn * 32 + ni * 16 + lr;          // block-local n (= k of next A)
        int kbh = nL >> 6;                        // 0 or 1
        int kloc = nL & 63;
        int cellbase = kbh * 8192 +
                       ((wm * 4 + mi) * 2 + (kloc >> 5)) * 512 +
                       (((kloc >> 3) & 3) * 16 + quad * 4) * 8 + (kloc & 7);
#pragma unroll
        for (int r = 0; r < 4; ++r)
          scratch[cellbase + r * 8] = f2bf(acc[mi][ni][r] * iv[ni]);
      }
    }
    __syncthreads();
    size_t obase = ((size_t)(bp * 2 + mb) * 16 + (n0 >> 6)) * 8192;
#pragma unroll
    for (int pass = 0; pass < 4; ++pass) {
      int fl = pass * 4096 + t * 8;
      *(u16x8*)&outb[obase + fl] = *(const u16x8*)&scratch[fl];
    }
  }
}

// ---------------------------------------------------------------------------
extern "C" void kernel_launch(void* const* d_in, const int* in_sizes, int n_in,
                              void* d_out, int out_size, void* d_ws, size_t ws_size,
                              hipStream_t stream) {
  const float* x = (const float*)d_in[0];
  const float* mixer = (const float*)d_in[1];
  const float* weight = (const float*)d_in[2];
  const float* wb = (const float*)d_in[3];
  const float* fw = (const float*)d_in[4];
  const float* bias = (const float*)d_in[5];
  const float* S = (const float*)d_in[6];
  float* out = (float*)d_out;

  char* ws = (char*)d_ws;
  size_t off = 0;
  auto take = [&](size_t bytes) -> char* {
    char* p = ws + off;
    off = (off + bytes + 255) & ~(size_t)255;
    return p;
  };
  float* e1 = (float*)take((size_t)B_ * P_ * N_ * 4);
  float* e2 = (float*)take((size_t)B_ * P_ * N_ * 4);
  float* sumb = (float*)take((size_t)B_ * P_ * N_ * 4);
  ushort_t* fwbf = (ushort_t*)take((size_t)P_ * F_ * KHOP * G_ * 2);
  ushort_t* xT = (ushort_t*)take((size_t)B_ * N_ * G_ * 2);
  ushort_t* expT = (ushort_t*)take((size_t)B_ * P_ * N_ * N_ * 2);
  ushort_t* sA = (ushort_t*)take((size_t)B_ * P_ * F_ * N_ * 2);
  ushort_t* sB = (ushort_t*)take((size_t)B_ * P_ * F_ * N_ * 2);

  k_prep<<<896, 256, 0, stream>>>(x, mixer, weight, wb, fw, e1, e2, fwbf, xT, sumb);
  k_att<<<dim3(4, 16, 8), 256, 0, stream>>>(e1, e2, S, expT, sumb);

  // Horner (1/rowsum folded into stored intermediates):
  // s3' = (fw3*x).inv ; s2' = (s3'*E^T + fw2*x).inv ;
  // s1' = (s2'*E^T + fw1*x).inv ; out = lrelu(s1'*E^T + fw0*x + bias)
  gemm_step<<<512, 512, 0, stream>>>(nullptr, expT, fwbf, xT, bias, sumb, sA, nullptr, 3, 0, 0);
  gemm_step<<<512, 512, 0, stream>>>(sA, expT, fwbf, xT, bias, sumb, sB, nullptr, 2, 1, 0);
  gemm_step<<<512, 512, 0, stream>>>(sB, expT, fwbf, xT, bias, sumb, sA, nullptr, 1, 1, 0);
  gemm_step<<<512, 512, 0, stream>>>(sA, expT, fwbf, xT, bias, sumb, nullptr, out, 0, 1, 1);
}

// Round 14
// 221.986 us; speedup vs baseline: 1.1634x; 1.1634x over previous
//
#include <hip/hip_runtime.h>
#include <hip/hip_bf16.h>

#define B_ 8
#define G_ 256
#define N_ 1024
#define P_ 4
#define F_ 256
#define KHOP 4
#define KG_ (KHOP * G_)   // 1024

// ---------------------------------------------------------------------------
// GLOBAL TILED LAYOUT (shared by expT, fwbf, xT, sA/sB):
//   matrix [R rows][C k-cols] -> tiles [R/128][C/64], each tile 8192 ushorts
//   (16 KB) contiguous.  Within a tile, element (r,k), r<128, k<64:
//     cell = (r>>4)*2 + (k>>5)            [0..15]
//     lane = ((k>>3)&3)*16 + (r&15)       [0..63]
//     e    = k&7
//     flat = cell*512 + lane*8 + e
//   One cell = one 16x32 MFMA fragment in exact lane order.
// ---------------------------------------------------------------------------

typedef unsigned short ushort_t;
typedef __bf16 bf16x8 __attribute__((ext_vector_type(8)));
typedef unsigned short u16x8 __attribute__((ext_vector_type(8)));
typedef float f32x4 __attribute__((ext_vector_type(4)));

__device__ __forceinline__ unsigned short f2bf(float f) {
  union { float fl; unsigned int i; } v; v.fl = f;
  return (unsigned short)((v.i + 0x7fffu + ((v.i >> 16) & 1u)) >> 16);
}

__device__ __forceinline__ void gload_lds16(const ushort_t* g, ushort_t* l) {
  __builtin_amdgcn_global_load_lds(
      (const __attribute__((address_space(1))) void*)g,
      (__attribute__((address_space(3))) void*)l, 16, 0, 0);
}

// ---------------------------------------------------------------------------
// K-PREP  (unchanged)
__global__ __launch_bounds__(256) void k_prep(
    const float* __restrict__ x, const float* __restrict__ mixer,
    const float* __restrict__ weight, const float* __restrict__ wb,
    const float* __restrict__ fw, float* __restrict__ e1, float* __restrict__ e2,
    ushort_t* __restrict__ fwbf, ushort_t* __restrict__ xT,
    float* __restrict__ sumb) {
  int blk = blockIdx.x;
  int t = threadIdx.x;
  if (blk < 128) {
    __shared__ float s1[G_], s2[G_];
    __shared__ float cred[2][4];
    int bp = blk >> 2;
    int nc = blk & 3;
    int b = bp >> 2, p = bp & (P_ - 1);
    int n = nc * 256 + t;
    float acc1 = 0.f, acc2 = 0.f;
    const float* wp = weight + (size_t)p * F_ * G_ + t;
    const float* mp = mixer + p * 2 * F_;
    for (int f = 0; f < F_; ++f) {
      float wv = wp[(size_t)f * G_];
      acc1 = fmaf(mp[f], wv, acc1);
      acc2 = fmaf(mp[F_ + f], wv, acc2);
    }
    s1[t] = acc1;
    s2[t] = acc2;
    float c1p = mp[t] * wb[p * F_ + t];
    float c2p = mp[F_ + t] * wb[p * F_ + t];
#pragma unroll
    for (int mask = 1; mask < 64; mask <<= 1) {
      c1p += __shfl_xor(c1p, mask, 64);
      c2p += __shfl_xor(c2p, mask, 64);
    }
    if ((t & 63) == 0) {
      cred[0][t >> 6] = c1p;
      cred[1][t >> 6] = c2p;
    }
    __syncthreads();
    float c1 = cred[0][0] + cred[0][1] + cred[0][2] + cred[0][3];
    float c2 = cred[1][0] + cred[1][1] + cred[1][2] + cred[1][3];
    const float* xb = x + (size_t)b * G_ * N_ + n;
    float a1 = 0.f, a2 = 0.f;
#pragma unroll 8
    for (int g = 0; g < G_; ++g) {
      float xv = xb[(size_t)g * N_];
      a1 = fmaf(s1[g], xv, a1);
      a2 = fmaf(s2[g], xv, a2);
    }
    e1[(size_t)bp * N_ + n] = c1 + a1;
    e2[(size_t)bp * N_ + n] = c2 + a2;
  } else if (blk < 256) {
    int tile = blk - 128;            // 0..127
    int p = tile >> 5;
    int mb = (tile >> 4) & 1;
    int kb = tile & 15;
    int w = t >> 6, lane = t & 63;
    size_t tbase = ((size_t)(p * 2 + mb) * 16 + kb) * 8192;
#pragma unroll
    for (int q = 0; q < 4; ++q) {
      int cell = q * 4 + w;
      int f = mb * 128 + (cell >> 1) * 16 + (lane & 15);
      int kg = kb * 64 + (cell & 1) * 32 + (lane >> 4) * 8;
      const float* s = fw + ((size_t)p * F_ + f) * KG_ + kg;
      float4 v0 = *(const float4*)&s[0];
      float4 v1 = *(const float4*)&s[4];
      u16x8 o;
      o[0] = f2bf(v0.x); o[1] = f2bf(v0.y); o[2] = f2bf(v0.z); o[3] = f2bf(v0.w);
      o[4] = f2bf(v1.x); o[5] = f2bf(v1.y); o[6] = f2bf(v1.z); o[7] = f2bf(v1.w);
      *(u16x8*)&fwbf[tbase + (size_t)cell * 512 + lane * 8] = o;
    }
  } else if (blk < 768) {
    __shared__ ushort_t tile[64][66];
    int idx = blk - 256;
    int n0 = (idx & 15) * 64;
    int g0 = ((idx >> 4) & 3) * 64;
    int b = idx >> 6;
    int rr = t >> 4, cc = (t & 15) * 4;
#pragma unroll
    for (int ps = 0; ps < 4; ++ps) {
      float4 v = *(const float4*)&x[((size_t)b * G_ + g0 + ps * 16 + rr) * N_ + n0 + cc];
      tile[ps * 16 + rr][cc] = f2bf(v.x);
      tile[ps * 16 + rr][cc + 1] = f2bf(v.y);
      tile[ps * 16 + rr][cc + 2] = f2bf(v.z);
      tile[ps * 16 + rr][cc + 3] = f2bf(v.w);
    }
    __syncthreads();
    int w = t >> 6, lane = t & 63;
    int nb = n0 >> 7;                 // 0..7
    int kb = g0 >> 6;                 // 0..3
    int rhalf = (n0 & 64) >> 4;       // 0 or 4
    size_t tbase = ((size_t)(b * 8 + nb) * 4 + kb) * 8192;
#pragma unroll
    for (int q = 0; q < 2; ++q) {
      int cl = q * 4 + w;                         // 0..7 local cell
      int cell = (rhalf + (cl >> 1)) * 2 + (cl & 1);
      int nl = (cl >> 1) * 16 + (lane & 15);      // 0..63 local n
      int gl = (cl & 1) * 32 + (lane >> 4) * 8;   // 0..56
      u16x8 v;
#pragma unroll
      for (int j = 0; j < 8; ++j) v[j] = tile[gl + j][nl];
      *(u16x8*)&xT[tbase + (size_t)cell * 512 + lane * 8] = v;
    }
  } else {
    int i = (blk - 768) * 256 + t;
    sumb[i] = 0.f;
  }
}

// ---------------------------------------------------------------------------
// K5 v3: one block serves ALL 4 p (S/mask read once) + XOR-SWIZZLED tile.
//   Element (j, il) stored at  j*72 + ((il>>3) ^ ((j>>2)&7))*8 + (il&7).
//   Writes: the XOR spreads the 16 cc4-lanes (j's 4 apart -> bank step 16,
//   formerly 8-16-way conflict) across 8 distinct 16B blocks -> ~4-way.
//   Dump reads: each u16x8 word = 8 contiguous il in ONE block -> single
//   aligned ds_read_b128 at the XOR'd block; row stride 36 dwords (≡4 mod
//   32) keeps reads ~2-way as before.  Same formula both sides.
__global__ __launch_bounds__(256) void k_att(const float* __restrict__ e1,
                                             const float* __restrict__ e2,
                                             const float* __restrict__ S,
                                             ushort_t* __restrict__ expT,
                                             float* __restrict__ sumb) {
  __shared__ ushort_t tile[256 * 72];  // swizzled [j][i]
  __shared__ float se1[P_][256];
  __shared__ float se2[P_][64];
  int b = blockIdx.z;          // 0..7
  int i0 = blockIdx.y * 64;    // k-dim chunk
  int j0 = blockIdx.x * 256;   // n-dim chunk
  int t = threadIdx.x;
  int rr = t >> 4;
  int cc4 = t & 15;
  int cc = cc4 * 4;

#pragma unroll
  for (int p = 0; p < P_; ++p) {
    int bp = b * 4 + p;
    se1[p][t] = e1[(size_t)bp * N_ + j0 + t];
    if (t < 64) se2[p][t] = e2[(size_t)bp * N_ + i0 + t];
  }
  __syncthreads();

  const float* Sb = S + (size_t)b * N_ * N_;
  unsigned long long mbits = 0ull;
#pragma unroll
  for (int js = 0; js < 4; ++js) {
#pragma unroll
    for (int ps = 0; ps < 4; ++ps) {
      int il = ps * 16 + rr;
      float4 s4 = *(const float4*)&Sb[(size_t)(i0 + il) * N_ + j0 + js * 64 + cc];
      float sv[4] = {s4.x, s4.y, s4.z, s4.w};
#pragma unroll
      for (int s = 0; s < 4; ++s)
        if (fabsf(sv[s]) > 1e-9f)
          mbits |= 1ull << (js * 16 + ps * 4 + s);
    }
  }

  int w = t >> 6, lane = t & 63;
  int kb = i0 >> 6;
  for (int p = 0; p < P_; ++p) {
    int bp = b * 4 + p;
    float re2[4];
#pragma unroll
    for (int ps = 0; ps < 4; ++ps) re2[ps] = se2[p][ps * 16 + rr];
    float psum[4] = {0.f, 0.f, 0.f, 0.f};
#pragma unroll
    for (int js = 0; js < 4; ++js) {
      float4 e1q = *(float4*)&se1[p][js * 64 + cc];
      float e1v[4] = {e1q.x, e1q.y, e1q.z, e1q.w};
#pragma unroll
      for (int ps = 0; ps < 4; ++ps) {
        int il = ps * 16 + rr;
        int blk8 = il >> 3;          // 0..7
        int e8 = il & 7;
#pragma unroll
        for (int s = 0; s < 4; ++s) {
          float v = e1v[s] + re2[ps];
          float l = v >= 0.f ? v : 0.2f * v;
          bool m = (mbits >> (js * 16 + ps * 4 + s)) & 1ull;
          float e = m ? __expf(l) : 0.f;
          psum[ps] += e;
          int j = js * 64 + cc + s;
          tile[j * 72 + ((blk8 ^ ((j >> 2) & 7)) * 8 + e8)] = f2bf(e);
        }
      }
    }
#pragma unroll
    for (int mask = 1; mask < 16; mask <<= 1) {
#pragma unroll
      for (int ps = 0; ps < 4; ++ps) psum[ps] += __shfl_xor(psum[ps], mask, 64);
    }
    if (cc4 == 0) {
#pragma unroll
      for (int ps = 0; ps < 4; ++ps)
        atomicAdd(&sumb[(size_t)bp * N_ + i0 + ps * 16 + rr], psum[ps]);
    }
    __syncthreads();
    // dump: tiled layout, one aligned b128 LDS read per word (swizzled)
#pragma unroll
    for (int hb = 0; hb < 2; ++hb) {
      size_t tbase = ((size_t)(bp * 8 + (j0 >> 7) + hb) * 16 + kb) * 8192;
#pragma unroll
      for (int q = 0; q < 4; ++q) {
        int cell = q * 4 + w;
        int jf = hb * 128 + (cell >> 1) * 16 + (lane & 15);
        int b0 = (cell & 1) * 4 + (lane >> 4);
        u16x8 v = *(const u16x8*)&tile[jf * 72 + (b0 ^ ((jf >> 2) & 7)) * 8];
        *(u16x8*)&expT[tbase + (size_t)cell * 512 + lane * 8] = v;
      }
    }
    __syncthreads();   // tile reads done before next p overwrites
  }
}

// ---------------------------------------------------------------------------
// K6 v7 (champion, reverted): A direct from global (frag-ordered tiled
// layout), B through double-buffered LDS via global_load_lds with counted
// vmcnt(12), 128x128 tile, 4 waves, 3 blocks/CU.
__global__ __launch_bounds__(256, 3) void gemm_step(
    const ushort_t* __restrict__ Aprev, const ushort_t* __restrict__ Bt,
    const ushort_t* __restrict__ fwbf, const ushort_t* __restrict__ xT,
    const float* __restrict__ bias, const float* __restrict__ sumb,
    ushort_t* __restrict__ outb, float* __restrict__ outf,
    int kslice, int has_prev, int last) {
  __shared__ ushort_t Bs[2][8192];   // 16 KB per buf
  // ---- XCD-aware decode: id&7 = xcd, 4 bps per XCD, 16 blocks per bp ----
  int id = blockIdx.x;
  int xcd = id & 7;
  int slot = id >> 3;            // 0..63
  int bp = xcd * 4 + (slot >> 4);
  int inner = slot & 15;
  int mb = inner >> 3;           // 0..1
  int m0 = mb * 128;
  int nb = inner & 7;            // 0..7
  int n0 = nb * 128;
  int p = bp & (P_ - 1), b = bp >> 2;
  int t = threadIdx.x;
  int lane = t & 63;
  int w = t >> 6;                // 0..3
  int wm = w >> 1, wn = w & 1;   // 2x2 wave grid, wave tile 64x64
  int lr = lane & 15, quad = lane >> 4;
  int laneoff = lane * 8;

  const ushort_t* A1 = has_prev ? (Aprev + (size_t)(bp * 2 + mb) * 16 * 8192) : fwbf;
  const ushort_t* A2 = fwbf + ((size_t)(p * 2 + mb) * 16 + kslice * 4) * 8192;
  const ushort_t* B1 = Bt + (size_t)(bp * 8 + nb) * 16 * 8192;
  const ushort_t* B2 = xT + (size_t)(b * 8 + nb) * 4 * 8192;

  const int ntA = has_prev ? (N_ / 64) : 0;   // 16 or 0
  const int NT = ntA + G_ / 64;               // 20 or 4

  f32x4 acc[4][4] = {};

  auto stageB = [&](int it, int buf) {
    const ushort_t* Bb = (it < ntA) ? B1 + (size_t)it * 8192
                                    : B2 + (size_t)(it - ntA) * 8192;
#pragma unroll
    for (int l = 0; l < 4; ++l) {
      int coff = (w * 4 + l) * 512;
      gload_lds16(Bb + coff + laneoff, &Bs[buf][coff]);
    }
  };

  // prologue: stage B tile 0 into buf 0 (4 loads/wave in flight)
  stageB(0, 0);
  int cur = 0;
  for (int it = 0; it < NT; ++it) {
    const ushort_t* At = (it < ntA) ? A1 + (size_t)it * 8192
                                    : A2 + (size_t)(it - ntA) * 8192;
    // A fragments: direct global->VGPR (wave-contiguous 1 KB each)
    u16x8 afr[2][4];
#pragma unroll
    for (int c = 0; c < 2; ++c)
#pragma unroll
      for (int mi = 0; mi < 4; ++mi)
        afr[c][mi] = *(const u16x8*)&At[(((wm * 4 + mi) * 2) + c) * 512 + laneoff];
    __builtin_amdgcn_sched_barrier(0);   // pin: afr issued before B_next DMA
    if (it + 1 < NT) {
      stageB(it + 1, cur ^ 1);                          // 4 more in flight
      asm volatile("s_waitcnt vmcnt(12)" ::: "memory"); // B_cur landed
    } else {
      asm volatile("s_waitcnt vmcnt(0)" ::: "memory");
    }
    __builtin_amdgcn_s_barrier();        // all waves' B_cur DMA visible
#pragma unroll
    for (int c = 0; c < 2; ++c) {
      bf16x8 bfr[4];
#pragma unroll
      for (int ni = 0; ni < 4; ++ni)
        bfr[ni] = __builtin_bit_cast(bf16x8,
            *(const u16x8*)&Bs[cur][(((wn * 4 + ni) * 2) + c) * 512 + lane * 8]);
#pragma unroll
      for (int mi = 0; mi < 4; ++mi) {
        bf16x8 af = __builtin_bit_cast(bf16x8, afr[c][mi]);
#pragma unroll
        for (int ni = 0; ni < 4; ++ni)
          acc[mi][ni] = __builtin_amdgcn_mfma_f32_16x16x32_bf16(af, bfr[ni], acc[mi][ni], 0, 0, 0);
      }
    }
    __builtin_amdgcn_s_barrier();        // reads done before buf overwritten
    cur ^= 1;
  }

  if (last) {
    float* Ob = outf + (size_t)bp * (F_ * N_);
#pragma unroll
    for (int mi = 0; mi < 4; ++mi) {
      int fbase = m0 + wm * 64 + mi * 16 + quad * 4;
#pragma unroll
      for (int ni = 0; ni < 4; ++ni) {
        int n = n0 + wn * 64 + ni * 16 + lr;
#pragma unroll
        for (int r = 0; r < 4; ++r) {
          float v = acc[mi][ni][r] + bias[fbase + r];
          Ob[(size_t)(fbase + r) * N_ + n] = v >= 0.f ? v : 0.01f * v;
        }
      }
    }
  } else {
    // epilogue via LDS scratch -> tiled global layout (next step's A)
    ushort_t* scratch = &Bs[0][0];   // 16384 ushorts = 32 KB
    float iv[4];
#pragma unroll
    for (int ni = 0; ni < 4; ++ni)
      iv[ni] = 1.0f / sumb[(size_t)bp * N_ + n0 + wn * 64 + ni * 16 + lr];
#pragma unroll
    for (int mi = 0; mi < 4; ++mi) {
#pragma unroll
      for (int ni = 0; ni < 4; ++ni) {
        int nL = wn * 64 + ni * 16 + lr;          // block-local n (= k of next A)
        int kbh = nL >> 6;                        // 0 or 1
        int kloc = nL & 63;
        int cellbase = kbh * 8192 +
                       ((wm * 4 + mi) * 2 + (kloc >> 5)) * 512 +
                       (((kloc >> 3) & 3) * 16 + quad * 4) * 8 + (kloc & 7);
#pragma unroll
        for (int r = 0; r < 4; ++r)
          scratch[cellbase + r * 8] = f2bf(acc[mi][ni][r] * iv[ni]);
      }
    }
    __syncthreads();
    size_t obase = ((size_t)(bp * 2 + mb) * 16 + (n0 >> 6)) * 8192;
#pragma unroll
    for (int pass = 0; pass < 8; ++pass) {
      int fl = pass * 2048 + t * 8;
      *(u16x8*)&outb[obase + fl] = *(const u16x8*)&scratch[fl];
    }
  }
}

// ---------------------------------------------------------------------------
extern "C" void kernel_launch(void* const* d_in, const int* in_sizes, int n_in,
                              void* d_out, int out_size, void* d_ws, size_t ws_size,
                              hipStream_t stream) {
  const float* x = (const float*)d_in[0];
  const float* mixer = (const float*)d_in[1];
  const float* weight = (const float*)d_in[2];
  const float* wb = (const float*)d_in[3];
  const float* fw = (const float*)d_in[4];
  const float* bias = (const float*)d_in[5];
  const float* S = (const float*)d_in[6];
  float* out = (float*)d_out;

  char* ws = (char*)d_ws;
  size_t off = 0;
  auto take = [&](size_t bytes) -> char* {
    char* p = ws + off;
    off = (off + bytes + 255) & ~(size_t)255;
    return p;
  };
  float* e1 = (float*)take((size_t)B_ * P_ * N_ * 4);
  float* e2 = (float*)take((size_t)B_ * P_ * N_ * 4);
  float* sumb = (float*)take((size_t)B_ * P_ * N_ * 4);
  ushort_t* fwbf = (ushort_t*)take((size_t)P_ * F_ * KHOP * G_ * 2);
  ushort_t* xT = (ushort_t*)take((size_t)B_ * N_ * G_ * 2);
  ushort_t* expT = (ushort_t*)take((size_t)B_ * P_ * N_ * N_ * 2);
  ushort_t* sA = (ushort_t*)take((size_t)B_ * P_ * F_ * N_ * 2);
  ushort_t* sB = (ushort_t*)take((size_t)B_ * P_ * F_ * N_ * 2);

  k_prep<<<896, 256, 0, stream>>>(x, mixer, weight, wb, fw, e1, e2, fwbf, xT, sumb);
  k_att<<<dim3(4, 16, 8), 256, 0, stream>>>(e1, e2, S, expT, sumb);

  // Horner (1/rowsum folded into stored intermediates):
  // s3' = (fw3*x).inv ; s2' = (s3'*E^T + fw2*x).inv ;
  // s1' = (s2'*E^T + fw1*x).inv ; out = lrelu(s1'*E^T + fw0*x + bias)
  gemm_step<<<512, 256, 0, stream>>>(nullptr, expT, fwbf, xT, bias, sumb, sA, nullptr, 3, 0, 0);
  gemm_step<<<512, 256, 0, stream>>>(sA, expT, fwbf, xT, bias, sumb, sB, nullptr, 2, 1, 0);
  gemm_step<<<512, 256, 0, stream>>>(sB, expT, fwbf, xT, bias, sumb, sA, nullptr, 1, 1, 0);
  gemm_step<<<512, 256, 0, stream>>>(sA, expT, fwbf, xT, bias, sumb, nullptr, out, 0, 1, 1);
}